// Round 5
// baseline (4575.299 us; speedup 1.0000x reference)
//
#include <hip/hip_runtime.h>
#include <math.h>

#define BB 32
#define TT 2048
#define HH 128

// LDS-only barrier: waits LDS ops (lgkmcnt), leaves global loads/stores in
// flight across the barrier.
#define LDS_BARRIER() asm volatile("s_waitcnt lgkmcnt(0)\n\ts_barrier" ::: "memory")

// DPP quad_perm. CTRL = p0|p1<<2|p2<<4|p3<<6. xor1=0xB1, xor2=0x4E,
// broadcast lane q within quad = q*0x55.
#define QPERM_F(v, CTRL)                                                      \
  __int_as_float(__builtin_amdgcn_update_dpp(                                 \
      0, __float_as_int(v), (CTRL), 0xF, 0xF, true))

// ---------------------------------------------------------------------------
// proj kernel: out[r, :] = emb[tokens[r]] @ W + bias   (layer-0 input proj)
// ---------------------------------------------------------------------------
__global__ __launch_bounds__(256) void proj_kernel(
    const float* __restrict__ src, const int* __restrict__ tokens,
    const float* __restrict__ W, const float* __restrict__ bias,
    float* __restrict__ out) {
  const int tid = threadIdx.x;
  const int jj = tid & 31;
  const int rr = tid >> 5;
  const int base = blockIdx.x * 64;

  __shared__ __align__(16) float srow[64][HH];
  __shared__ int stok[64];

  if (tid < 64) stok[tid] = tokens[base + tid];
  __syncthreads();

#pragma unroll
  for (int i = 0; i < 8; ++i) {
    int idx = tid + i * 256;
    int row = idx >> 5;
    int c4 = idx & 31;
    const float* s = src + (size_t)stok[row] * HH;
    *(float4*)&srow[row][c4 * 4] = *(const float4*)&s[c4 * 4];
  }
  __syncthreads();

  float4 b4 = *(const float4*)&bias[jj * 4];
  float4 acc[8];
#pragma unroll
  for (int i = 0; i < 8; ++i) acc[i] = b4;

  for (int k = 0; k < HH; ++k) {
    float4 w4 = *(const float4*)&W[k * HH + jj * 4];
#pragma unroll
    for (int i = 0; i < 8; ++i) {
      float e = srow[rr * 8 + i][k];
      acc[i].x += e * w4.x;
      acc[i].y += e * w4.y;
      acc[i].z += e * w4.z;
      acc[i].w += e * w4.w;
    }
  }

#pragma unroll
  for (int i = 0; i < 8; ++i) {
    int row = base + rr * 8 + i;
    *(float4*)&out[(size_t)row * HH + jj * 4] = acc[i];
  }
}

// ---------------------------------------------------------------------------
// rnn_fused: both layers in one kernel, wave-specialized, layer 1 one phase
// behind layer 0. One block (1024 thr / 16 waves) per batch.
//   threads 0..511  (L0): h0[t] = tanh(xp0[t] + h0[t-1]@Wh0)       [v3 form]
//   threads 512..1023(L1): h1[t] = tanh(y0[t]@Wx1 + b1 + h1[t-1]@Wh1)
// y0[t] == h0[t] is consumed straight from L0's LDS double buffer — no
// global y0 store, no separate proj1 dispatch. Phases: TT+1 = 2049 barriers
// instead of 2*TT (round-4 evidence: per-phase cost is a ~700-cyc dependent
// chain, so halving phase count ~halves time).
// Per-branch-local weight arrays keep live VGPRs ~100 (round-2 lesson:
// unified 128-float array spilled to scratch).
// Buffer parity: at phase ph, hs*[ph&1] holds state[ph-1]; ph&1 hand-folded
// to the compile-time (Q&1) since ph0 steps by 4.
// ---------------------------------------------------------------------------
__global__ __launch_bounds__(1024) void rnn_fused(
    const float* __restrict__ xp0, float* __restrict__ out,
    const float* __restrict__ Wh0, const float* __restrict__ Wx1,
    const float* __restrict__ Wh1, const float* __restrict__ b1,
    const int* __restrict__ tokens) {
  const int b = blockIdx.x;
  const int tid = threadIdx.x;
  const bool isL0 = (tid < 512);
  const int sub = tid & 511;
  const int j = sub >> 2;   // column 0..127
  const int p = sub & 3;    // k-slice 0..3
  const int lane = tid & 63;

  // Mask bitmask: lane l holds bits for t in [32l, 32l+32).
  const int* tok = tokens + b * TT;
  unsigned bits = 0;
#pragma unroll
  for (int i = 0; i < 8; ++i) {
    int4 tk = *(const int4*)&tok[lane * 32 + i * 4];
    bits |= (unsigned)(tk.x != 0) << (i * 4 + 0);
    bits |= (unsigned)(tk.y != 0) << (i * 4 + 1);
    bits |= (unsigned)(tk.z != 0) << (i * 4 + 2);
    bits |= (unsigned)(tk.w != 0) << (i * 4 + 3);
  }

  __shared__ __align__(16) float hs0[2][HH];
  __shared__ __align__(16) float hs1[2][HH];
  if (tid < HH) {
    hs0[0][tid] = 0.0f;
    hs0[1][tid] = 0.0f;
    hs1[0][tid] = 0.0f;
    hs1[1][tid] = 0.0f;
  }
  LDS_BARRIER();

  if (isL0) {
    // ---------------- layer 0 (v3 structure) ----------------
    float w0[32];
#pragma unroll
    for (int c = 0; c < 32; ++c) {
      int k = 16 * (c >> 2) + 4 * p + (c & 3);
      w0[c] = Wh0[k * HH + j];
    }
    const float* xb = xp0 + (size_t)b * TT * HH;
    float h0 = 0.0f;
    float xc = xb[(size_t)p * HH + j];  // lane p holds row t0+p

#define L0_STEP(Q)                                                            \
  {                                                                           \
    const int t = t0 + (Q);                                                   \
    const float* hb = hs0[(Q) & 1];                                           \
    float a0 = 0.f, a1 = 0.f, a2 = 0.f, a3 = 0.f;                             \
    _Pragma("unroll") for (int i = 0; i < 8; ++i) {                           \
      float4 hv = *(const float4*)&hb[16 * i + 4 * p];                        \
      a0 += hv.x * w0[4 * i + 0];                                             \
      a1 += hv.y * w0[4 * i + 1];                                             \
      a2 += hv.z * w0[4 * i + 2];                                             \
      a3 += hv.w * w0[4 * i + 3];                                             \
    }                                                                         \
    float acc = (a0 + a1) + (a2 + a3);                                        \
    acc += QPERM_F(acc, 0xB1);                                                \
    acc += QPERM_F(acc, 0x4E);                                                \
    float sx = acc + QPERM_F(xc, (Q) * 0x55);                                 \
    unsigned word = (unsigned)__builtin_amdgcn_readlane((int)bits, t >> 5);   \
    int m = (word >> (t & 31)) & 1;                                           \
    float e = __expf(-2.0f * fabsf(sx));                                      \
    float th = copysignf((1.0f - e) * __builtin_amdgcn_rcpf(1.0f + e), sx);   \
    h0 = m ? th : h0;                                                         \
    if (p == 0) hs0[((Q) + 1) & 1][j] = h0;                                   \
    LDS_BARRIER();                                                            \
  }

    for (int t0 = 0; t0 < TT; t0 += 4) {
      float xn = 0.0f;
      if (t0 + 4 < TT) xn = xb[(size_t)(t0 + 4 + p) * HH + j];
      L0_STEP(0)
      L0_STEP(1)
      L0_STEP(2)
      L0_STEP(3)
      xc = xn;
    }
#undef L0_STEP
    // L0 waves exit; barrier counts match L1's in-loop barriers (2048+1 each).
  } else {
    // ---------------- layer 1 (one phase behind) ----------------
    float wx[32], wh[32];
#pragma unroll
    for (int c = 0; c < 32; ++c) {
      int k = 16 * (c >> 2) + 4 * p + (c & 3);
      wx[c] = Wx1[k * HH + j];
      wh[c] = Wh1[k * HH + j];
    }
    const float bias1 = b1[j];
    float* ob = out + (size_t)b * TT * HH;
    float h1 = 0.0f;

// Phase PH (parity PAR == PH&1): consumes y0[PH-1] from hs0[PAR] and
// h1[PH-2] from hs1[PAR]; publishes h1[PH-1] into hs1[PAR^1]; stores y1.
#define L1_BODY(PH, PAR)                                                      \
  {                                                                           \
    const int t = (PH)-1;                                                     \
    const float* yb = hs0[(PAR)];                                             \
    const float* hb = hs1[(PAR)];                                             \
    float a0 = 0.f, a1 = 0.f, a2 = 0.f, a3 = 0.f;                             \
    float c0 = 0.f, c1 = 0.f, c2 = 0.f, c3 = 0.f;                             \
    _Pragma("unroll") for (int i = 0; i < 8; ++i) {                           \
      float4 yv = *(const float4*)&yb[16 * i + 4 * p];                        \
      float4 hv = *(const float4*)&hb[16 * i + 4 * p];                        \
      a0 += yv.x * wx[4 * i + 0];                                             \
      a1 += yv.y * wx[4 * i + 1];                                             \
      a2 += yv.z * wx[4 * i + 2];                                             \
      a3 += yv.w * wx[4 * i + 3];                                             \
      c0 += hv.x * wh[4 * i + 0];                                             \
      c1 += hv.y * wh[4 * i + 1];                                             \
      c2 += hv.z * wh[4 * i + 2];                                             \
      c3 += hv.w * wh[4 * i + 3];                                             \
    }                                                                         \
    float acc = ((a0 + a1) + (a2 + a3)) + ((c0 + c1) + (c2 + c3));            \
    acc += QPERM_F(acc, 0xB1);                                                \
    acc += QPERM_F(acc, 0x4E);                                                \
    float sx = acc + bias1;                                                   \
    unsigned word = (unsigned)__builtin_amdgcn_readlane((int)bits, t >> 5);   \
    int m = (word >> (t & 31)) & 1;                                           \
    float e = __expf(-2.0f * fabsf(sx));                                      \
    float th = copysignf((1.0f - e) * __builtin_amdgcn_rcpf(1.0f + e), sx);   \
    h1 = m ? th : h1;                                                         \
    if (p == 0) {                                                             \
      ob[(size_t)t * HH + j] = h1;                                            \
      hs1[(PAR) ^ 1][j] = h1;                                                 \
    }                                                                         \
  }

    for (int ph0 = 0; ph0 < TT; ph0 += 4) {
      if (ph0 > 0) {
        L1_BODY(ph0 + 0, 0)
      }
      LDS_BARRIER();
      L1_BODY(ph0 + 1, 1)
      LDS_BARRIER();
      L1_BODY(ph0 + 2, 0)
      LDS_BARRIER();
      L1_BODY(ph0 + 3, 1)
      LDS_BARRIER();
    }
    // Final phase PH = TT (parity 0): compute t = TT-1; no trailing barrier.
    L1_BODY(TT, 0)
#undef L1_BODY
  }
}

extern "C" void kernel_launch(void* const* d_in, const int* in_sizes, int n_in,
                              void* d_out, int out_size, void* d_ws,
                              size_t ws_size, hipStream_t stream) {
  const int* tokens = (const int*)d_in[0];
  const float* emb = (const float*)d_in[1];
  const float* Wx0 = (const float*)d_in[2];
  const float* Wh0 = (const float*)d_in[3];
  const float* b0 = (const float*)d_in[4];
  const float* Wx1 = (const float*)d_in[5];
  const float* Wh1 = (const float*)d_in[6];
  const float* b1 = (const float*)d_in[7];
  float* out = (float*)d_out;
  float* ws = (float*)d_ws;  // 32 MB: xp0 (read-only in rnn_fused)

  const int rows = BB * TT;            // 65536
  const int proj_blocks = rows / 64;   // 1024

  // xp0 = emb[tokens] @ Wx0 + b0
  proj_kernel<<<proj_blocks, 256, 0, stream>>>(emb, tokens, Wx0, b0, ws);
  // Fused two-layer recurrence; writes y1 to out.
  rnn_fused<<<BB, 1024, 0, stream>>>(ws, out, Wh0, Wx1, Wh1, b1, tokens);
}

// Round 6
// 1492.981 us; speedup vs baseline: 3.0645x; 3.0645x over previous
//
#include <hip/hip_runtime.h>
#include <math.h>

#define BB 32
#define TT 2048
#define HH 128

// LDS-only barrier: waits LDS ops (lgkmcnt), leaves global loads/stores in
// flight across the barrier.
#define LDS_BARRIER() asm volatile("s_waitcnt lgkmcnt(0)\n\ts_barrier" ::: "memory")

// DPP helper. quad_perm CTRL = p0|p1<<2|p2<<4|p3<<6 (0xB1 = xor1, 0x4E = xor2);
// 0x141 = row_half_mirror (lane i <-> 7-i within each 8-lane half-row).
#define DPP_F(v, CTRL)                                                        \
  __int_as_float(__builtin_amdgcn_update_dpp(                                 \
      0, __float_as_int(v), (CTRL), 0xF, 0xF, true))

// ---------------------------------------------------------------------------
// proj kernel: out[r, :] = src_row(r) @ W + bias
// ---------------------------------------------------------------------------
template <bool GATHER>
__global__ __launch_bounds__(256) void proj_kernel(
    const float* __restrict__ src, const int* __restrict__ tokens,
    const float* __restrict__ W, const float* __restrict__ bias,
    float* __restrict__ out) {
  const int tid = threadIdx.x;
  const int jj = tid & 31;
  const int rr = tid >> 5;
  const int base = blockIdx.x * 64;

  __shared__ __align__(16) float srow[64][HH];
  __shared__ int stok[64];

  if (GATHER) {
    if (tid < 64) stok[tid] = tokens[base + tid];
    __syncthreads();
  }

#pragma unroll
  for (int i = 0; i < 8; ++i) {
    int idx = tid + i * 256;
    int row = idx >> 5;
    int c4 = idx & 31;
    const float* s = GATHER ? (src + (size_t)stok[row] * HH)
                            : (src + (size_t)(base + row) * HH);
    *(float4*)&srow[row][c4 * 4] = *(const float4*)&s[c4 * 4];
  }
  __syncthreads();

  float4 b4 = *(const float4*)&bias[jj * 4];
  float4 acc[8];
#pragma unroll
  for (int i = 0; i < 8; ++i) acc[i] = b4;

  for (int k = 0; k < HH; ++k) {
    float4 w4 = *(const float4*)&W[k * HH + jj * 4];
#pragma unroll
    for (int i = 0; i < 8; ++i) {
      float e = srow[rr * 8 + i][k];
      acc[i].x += e * w4.x;
      acc[i].y += e * w4.y;
      acc[i].z += e * w4.z;
      acc[i].w += e * w4.w;
    }
  }

#pragma unroll
  for (int i = 0; i < 8; ++i) {
    int row = base + rr * 8 + i;
    *(float4*)&out[(size_t)row * HH + jj * 4] = acc[i];
  }
}

// ---------------------------------------------------------------------------
// rnn kernel v6: reuse=2, k-split=8.
// Phase-cost law (r3/r4/r5 evidence): phase ~= waves * ds_read_b128/thread
// * 12 cyc (LDS issue pipe), chain hidden iff >=2 waves/SIMD.
//   v3: 8w*8=64 instr -> 748 cyc. Here: 8w*4=32 instr -> ~420 cyc target.
// 512 threads, one block/batch. Thread (cp=tid>>3, p=tid&7) owns cols
// {cp, cp+64}; holds 16 h-elems (k = 32i+4p+r, i,r in [0,4)) -> 4 b128
// conflict-free reads (8 distinct addrs * 8-way broadcast), 32 weight VGPRs.
// 8-lane reduce: DPP xor1, xor2, row_half_mirror. Lane carries h for
// colsel = cp + 64*(p&1); one tanh/thread; lanes p<2 publish + store.
// In-place (reads x rows t0+4.., writes row t); column-exclusive ownership.
// ---------------------------------------------------------------------------
__global__ __launch_bounds__(512) void rnn_kernel(
    float* io, const float* __restrict__ Wh, const int* __restrict__ tokens) {
  const int b = blockIdx.x;
  const int tid = threadIdx.x;
  const int cp = tid >> 3;                 // column 0..63
  const int p = tid & 7;                   // k-slice 0..7
  const int lane = tid & 63;
  const int colsel = cp + ((p & 1) << 6);  // even p -> cp, odd p -> cp+64

  // 32 weights: w0/w1[c] <-> k = 32*(c>>2) + 4*p + (c&3), cols cp / cp+64.
  float w0[16], w1[16];
#pragma unroll
  for (int c = 0; c < 16; ++c) {
    int k = 32 * (c >> 2) + 4 * p + (c & 3);
    w0[c] = Wh[k * HH + cp];
    w1[c] = Wh[k * HH + cp + 64];
  }

  // Mask bitmask: lane l holds bits for t in [32l, 32l+32).
  const int* tok = tokens + b * TT;
  unsigned bits = 0;
#pragma unroll
  for (int i = 0; i < 8; ++i) {
    int4 tk = *(const int4*)&tok[lane * 32 + i * 4];
    bits |= (unsigned)(tk.x != 0) << (i * 4 + 0);
    bits |= (unsigned)(tk.y != 0) << (i * 4 + 1);
    bits |= (unsigned)(tk.z != 0) << (i * 4 + 2);
    bits |= (unsigned)(tk.w != 0) << (i * 4 + 3);
  }

  __shared__ __align__(16) float hs[2][HH];
  if (tid < HH) hs[0][tid] = 0.0f;

  float* xp = io + (size_t)b * TT * HH;

  // x ring: xr[i] = x[t0+i][colsel], distance-4 prefetch.
  float xr[4];
#pragma unroll
  for (int i = 0; i < 4; ++i) xr[i] = xp[(size_t)i * HH + colsel];

  float h = 0.0f;
  LDS_BARRIER();

#define RNN_STEP(Q)                                                           \
  {                                                                           \
    const int t = t0 + (Q);                                                   \
    const float* hb = hs[(Q) & 1];                                            \
    float a0 = 0.f, a1 = 0.f, a2 = 0.f, a3 = 0.f;                             \
    float c0 = 0.f, c1 = 0.f, c2 = 0.f, c3 = 0.f;                             \
    _Pragma("unroll") for (int i = 0; i < 4; ++i) {                           \
      float4 hv = *(const float4*)&hb[32 * i + 4 * p];                        \
      a0 += hv.x * w0[4 * i + 0];                                             \
      a1 += hv.y * w0[4 * i + 1];                                             \
      a2 += hv.z * w0[4 * i + 2];                                             \
      a3 += hv.w * w0[4 * i + 3];                                             \
      c0 += hv.x * w1[4 * i + 0];                                             \
      c1 += hv.y * w1[4 * i + 1];                                             \
      c2 += hv.z * w1[4 * i + 2];                                             \
      c3 += hv.w * w1[4 * i + 3];                                             \
    }                                                                         \
    float accA = (a0 + a1) + (a2 + a3);                                       \
    float accB = (c0 + c1) + (c2 + c3);                                       \
    accA += DPP_F(accA, 0xB1);  /* + lane^1 (quad) */                         \
    accB += DPP_F(accB, 0xB1);                                                \
    accA += DPP_F(accA, 0x4E);  /* + lane^2 (quad) */                         \
    accB += DPP_F(accB, 0x4E);                                                \
    accA += DPP_F(accA, 0x141); /* + across quads: i <-> 7-i */               \
    accB += DPP_F(accB, 0x141);                                               \
    float acc = (p & 1) ? accB : accA;                                        \
    float sx = acc + xr[(Q)];                                                 \
    unsigned word = (unsigned)__builtin_amdgcn_readlane((int)bits, t >> 5);   \
    int m = (word >> (t & 31)) & 1;                                           \
    float e = __expf(-2.0f * fabsf(sx));                                      \
    float th = copysignf((1.0f - e) * __builtin_amdgcn_rcpf(1.0f + e), sx);   \
    h = m ? th : h;                                                           \
    if (p < 2) {                                                              \
      xp[(size_t)t * HH + colsel] = h;  /* ys output (in-place) */            \
      hs[((Q) + 1) & 1][colsel] = h;    /* publish h */                       \
    }                                                                         \
    LDS_BARRIER();                                                            \
  }

  for (int t0 = 0; t0 < TT; t0 += 4) {
    float xn0 = 0.f, xn1 = 0.f, xn2 = 0.f, xn3 = 0.f;
    if (t0 + 4 < TT) {
      xn0 = xp[(size_t)(t0 + 4) * HH + colsel];
      xn1 = xp[(size_t)(t0 + 5) * HH + colsel];
      xn2 = xp[(size_t)(t0 + 6) * HH + colsel];
      xn3 = xp[(size_t)(t0 + 7) * HH + colsel];
    }
    RNN_STEP(0)
    RNN_STEP(1)
    RNN_STEP(2)
    RNN_STEP(3)
    xr[0] = xn0;
    xr[1] = xn1;
    xr[2] = xn2;
    xr[3] = xn3;
  }
#undef RNN_STEP
}

extern "C" void kernel_launch(void* const* d_in, const int* in_sizes, int n_in,
                              void* d_out, int out_size, void* d_ws,
                              size_t ws_size, hipStream_t stream) {
  const int* tokens = (const int*)d_in[0];
  const float* emb = (const float*)d_in[1];
  const float* Wx0 = (const float*)d_in[2];
  const float* Wh0 = (const float*)d_in[3];
  const float* b0 = (const float*)d_in[4];
  const float* Wx1 = (const float*)d_in[5];
  const float* Wh1 = (const float*)d_in[6];
  const float* b1 = (const float*)d_in[7];
  float* out = (float*)d_out;
  float* ws = (float*)d_ws;  // 32 MB: xp0 -> ys0 (in-place)

  const int rows = BB * TT;            // 65536
  const int proj_blocks = rows / 64;   // 1024

  proj_kernel<true><<<proj_blocks, 256, 0, stream>>>(emb, tokens, Wx0, b0, ws);
  rnn_kernel<<<BB, 512, 0, stream>>>(ws, Wh0, tokens);
  proj_kernel<false><<<proj_blocks, 256, 0, stream>>>(ws, nullptr, Wx1, b1, out);
  rnn_kernel<<<BB, 512, 0, stream>>>(out, Wh1, tokens);
}